// Round 8
// baseline (274.168 us; speedup 1.0000x reference)
//
#include <hip/hip_runtime.h>

#define N_IMG 4
#define E_DIM 16
#define G_PIX 80000               // float4 groups per image-channel (320000/4)
#define C_CLS 20
#define CK 19                     // classes 1..19 (IGNORE = 0)
#define NREP 8                    // LDS replica count for atomic binning
#define EG 4                      // channels per phase-A block
#define NEG (E_DIM / EG)          // 4 channel groups
#define SL1 64                    // phase-A pixel slices per (image, egroup)
#define R1 (G_PIX / SL1)          // 1250 groups per phase-A block (exact)
#define GRID_B (SL1 * NEG * N_IMG)   // 1024 blocks = exactly 4 per CU
#define SL2 (GRID_B / N_IMG)      // 256 phase-B slices per image
#define R2 ((G_PIX + SL2 - 1) / SL2) // 313 (tail-checked)
#define MSTRIDE 17                // lmean stride: 20 labels -> 20 distinct banks
#define LS_SLOT 5                 // u64 slots per (class, replica)
#define SCALE_F 16777216.0f       // 2^24 fixed-point scale
#define INV_SCALE (1.0f / 16777216.0f)

// ws float layout: sums[n][c][e], counts[n][c], loss, pad, barrier state
#define SUMS_OFF 0
#define CNT_OFF (N_IMG * C_CLS * E_DIM)       // 1280
#define LOSS_OFF (CNT_OFF + N_IMG * C_CLS)    // 1360
#define BAR_OFF 1364                          // [0]=arrive1 [1]=flag1 [2]=arrive2
#define WS_FLOATS (BAR_OFF + 3)

static_assert(G_PIX % SL1 == 0, "phase-A slicing must be exact");

// Persistent fused kernel. Residency: 1024 blocks, 256 threads, launch_bounds(256,4)
// -> exactly 4 blocks/CU on 256 CUs; manual grid barrier is safe.
// NOTE (measured r2): float LDS atomicAdd = CAS loop (310us). Integer ds_add is native.
__global__ __launch_bounds__(256, 4) void k_fused(const float* __restrict__ emb,
                                                  const int* __restrict__ target,
                                                  float* __restrict__ ws,
                                                  float* __restrict__ out) {
    __shared__ unsigned long long ls[C_CLS][NREP][LS_SLOT];   // 6400 B
    __shared__ unsigned int lc[C_CLS][NREP];                  // 640 B
    __shared__ float lmean[C_CLS * MSTRIDE];
    __shared__ float lw[C_CLS];
    __shared__ float red[256];

    const int tid = threadIdx.x;
    const int b = blockIdx.x;
    const int n = b & 3;

    // ================= phase A: per-class sums + counts (integer LDS binning) ========
    {
        const int eg = (b >> 2) & (NEG - 1);
        const int slice = b >> 4;              // 0..SL1-1
        const int e0 = eg * EG;

        unsigned long long* lsf = &ls[0][0][0];
        for (int i = tid; i < C_CLS * NREP * LS_SLOT; i += 256) lsf[i] = 0ull;
        for (int i = tid; i < C_CLS * NREP; i += 256) (&lc[0][0])[i] = 0u;
        __syncthreads();

        const float4* emb0 = (const float4*)emb + ((size_t)(n * E_DIM + e0)) * G_PIX;
        const int4* tgt4 = (const int4*)target + (size_t)n * G_PIX;
        const int r = tid & (NREP - 1);

#define QADD(p, idx, val) \
    atomicAdd((p) + (idx), (unsigned long long)(long long)__float2int_rn((val) * SCALE_F))

        const int g1 = (slice + 1) * R1;
        for (int g = slice * R1 + tid; g < g1; g += 256) {
            const int4 lb = tgt4[g];
            const float4 v0 = emb0[g];
            const float4 v1 = emb0[G_PIX + g];
            const float4 v2 = emb0[2 * G_PIX + g];
            const float4 v3 = emb0[3 * G_PIX + g];

            unsigned long long* px = &ls[lb.x][r][0];
            unsigned long long* py = &ls[lb.y][r][0];
            unsigned long long* pz = &ls[lb.z][r][0];
            unsigned long long* pw = &ls[lb.w][r][0];
            QADD(px, 0, v0.x); QADD(px, 1, v1.x); QADD(px, 2, v2.x); QADD(px, 3, v3.x);
            QADD(py, 0, v0.y); QADD(py, 1, v1.y); QADD(py, 2, v2.y); QADD(py, 3, v3.y);
            QADD(pz, 0, v0.z); QADD(pz, 1, v1.z); QADD(pz, 2, v2.z); QADD(pz, 3, v3.z);
            QADD(pw, 0, v0.w); QADD(pw, 1, v1.w); QADD(pw, 2, v2.w); QADD(pw, 3, v3.w);
            if (eg == 0) {
                atomicAdd(&lc[lb.x][r], 1u); atomicAdd(&lc[lb.y][r], 1u);
                atomicAdd(&lc[lb.z][r], 1u); atomicAdd(&lc[lb.w][r], 1u);
            }
        }
#undef QADD
        __syncthreads();

        for (int i = tid; i < C_CLS * EG; i += 256) {
            const int c = i >> 2, e1 = i & 3;
            long long q = 0;
#pragma unroll
            for (int rr = 0; rr < NREP; rr++) q += (long long)ls[c][rr][e1];
            atomicAdd(ws + SUMS_OFF + (n * C_CLS + c) * E_DIM + e0 + e1, (float)q * INV_SCALE);
        }
        if (eg == 0) {
            for (int c = tid; c < C_CLS; c += 256) {
                unsigned int s = 0;
#pragma unroll
                for (int rr = 0; rr < NREP; rr++) s += lc[c][rr];
                atomicAdd(ws + CNT_OFF + n * C_CLS + c, (float)s);
            }
        }
    }

    // ================= manual grid barrier (agent-scope, graph-safe) =================
    unsigned* bar = (unsigned*)(ws + BAR_OFF);
    __syncthreads();
    if (tid == 0) {
        __threadfence();
        const unsigned arr = __hip_atomic_fetch_add(&bar[0], 1u, __ATOMIC_ACQ_REL,
                                                    __HIP_MEMORY_SCOPE_AGENT);
        if (arr == GRID_B - 1) {
            __hip_atomic_store(&bar[1], 1u, __ATOMIC_RELEASE, __HIP_MEMORY_SCOPE_AGENT);
        } else {
            long spins = 0;
            while (__hip_atomic_load(&bar[1], __ATOMIC_ACQUIRE,
                                     __HIP_MEMORY_SCOPE_AGENT) == 0u) {
                __builtin_amdgcn_s_sleep(8);
                if (++spins > (1L << 26)) break;   // failsafe: no infinite hang
            }
        }
    }
    __syncthreads();

    // ================= phase B: means + push/reg terms + variance term ===============
    {
        const int s2 = b >> 2;                 // 0..SL2-1
        float* gsum = ws + SUMS_OFF + n * C_CLS * E_DIM;
        float* gcnt = ws + CNT_OFF + n * C_CLS;

        // agent-scope loads: sums/counts were written by other XCDs (L2s not coherent)
        for (int i = tid; i < C_CLS * E_DIM; i += 256) {
            const int c = i >> 4, e = i & 15;
            const float cnt = __hip_atomic_load(&gcnt[c], __ATOMIC_RELAXED,
                                                __HIP_MEMORY_SCOPE_AGENT);
            const float s = __hip_atomic_load(&gsum[i], __ATOMIC_RELAXED,
                                              __HIP_MEMORY_SCOPE_AGENT);
            lmean[c * MSTRIDE + e] = (cnt > 0.f) ? s / cnt : 0.f;
        }
        if (tid < C_CLS) {
            const float cnt = __hip_atomic_load(&gcnt[tid], __ATOMIC_RELAXED,
                                                __HIP_MEMORY_SCOPE_AGENT);
            // lw[0] = 0 masks IGNORE pixels branchlessly
            lw[tid] = (tid != 0 && cnt > 0.f) ? 1.0f / (cnt * (float)CK) : 0.f;
        }
        __syncthreads();

        float acc = 0.f;
        if (b < N_IMG) {
            // one block per image computes push + regularizer terms
            for (int idx = tid; idx < CK * CK; idx += 256) {
                const int i = idx / CK + 1, j = idx % CK + 1;
                if (i != j) {
                    float sq = 0.f;
#pragma unroll
                    for (int e = 0; e < E_DIM; e++) {
                        const float d = lmean[i * MSTRIDE + e] - lmean[j * MSTRIDE + e];
                        sq += d * d;
                    }
                    const float dm = sqrtf(sq);
                    const float h = fmaxf(3.0f - dm, 0.f);   // 2*DELTA_DIST = 3
                    acc += h * h;
                }
            }
            acc *= 1.0f / (float)(CK * (CK - 1));            // BETA = 1
            float racc = 0.f;
            for (int c = tid + 1; c < C_CLS; c += 256) {
                float sq = 0.f;
#pragma unroll
                for (int e = 0; e < E_DIM; e++) {
                    const float m = lmean[c * MSTRIDE + e];
                    sq += m * m;
                }
                racc += sqrtf(sq);
            }
            acc += 0.001f * racc / (float)CK;                // GAMMA = 0.001
        }

        const float4* emb4 = (const float4*)emb + (size_t)n * E_DIM * G_PIX;
        const int4* tgt4 = (const int4*)target + (size_t)n * G_PIX;
        const int gend0 = (s2 + 1) * R2;
        const int gend = (gend0 < G_PIX) ? gend0 : G_PIX;
        for (int g = s2 * R2 + tid; g < gend; g += 256) {
            const int4 lb = tgt4[g];
            const int bx = lb.x * MSTRIDE, by = lb.y * MSTRIDE;
            const int bz = lb.z * MSTRIDE, bw = lb.w * MSTRIDE;
            float sx = 0.f, sy = 0.f, sz = 0.f, sw = 0.f;
            // 4-channel batches: caps live VGPRs (16 data regs) under the 128 cap
#pragma unroll 1
            for (int eb = 0; eb < E_DIM; eb += 4) {
                const float4 a0 = emb4[(size_t)(eb + 0) * G_PIX + g];
                const float4 a1 = emb4[(size_t)(eb + 1) * G_PIX + g];
                const float4 a2 = emb4[(size_t)(eb + 2) * G_PIX + g];
                const float4 a3 = emb4[(size_t)(eb + 3) * G_PIX + g];
                float d;
                d = a0.x - lmean[bx + eb];     sx += d * d;
                d = a1.x - lmean[bx + eb + 1]; sx += d * d;
                d = a2.x - lmean[bx + eb + 2]; sx += d * d;
                d = a3.x - lmean[bx + eb + 3]; sx += d * d;
                d = a0.y - lmean[by + eb];     sy += d * d;
                d = a1.y - lmean[by + eb + 1]; sy += d * d;
                d = a2.y - lmean[by + eb + 2]; sy += d * d;
                d = a3.y - lmean[by + eb + 3]; sy += d * d;
                d = a0.z - lmean[bz + eb];     sz += d * d;
                d = a1.z - lmean[bz + eb + 1]; sz += d * d;
                d = a2.z - lmean[bz + eb + 2]; sz += d * d;
                d = a3.z - lmean[bz + eb + 3]; sz += d * d;
                d = a0.w - lmean[bw + eb];     sw += d * d;
                d = a1.w - lmean[bw + eb + 1]; sw += d * d;
                d = a2.w - lmean[bw + eb + 2]; sw += d * d;
                d = a3.w - lmean[bw + eb + 3]; sw += d * d;
            }
            float h;
            h = fmaxf(sqrtf(sx) - 0.5f, 0.f); acc += h * h * lw[lb.x];
            h = fmaxf(sqrtf(sy) - 0.5f, 0.f); acc += h * h * lw[lb.y];
            h = fmaxf(sqrtf(sz) - 0.5f, 0.f); acc += h * h * lw[lb.z];
            h = fmaxf(sqrtf(sw) - 0.5f, 0.f); acc += h * h * lw[lb.w];
        }

        red[tid] = acc;
        __syncthreads();
        for (int s = 128; s > 0; s >>= 1) {
            if (tid < s) red[tid] += red[tid + s];
            __syncthreads();
        }
        if (tid == 0) {
            atomicAdd(ws + LOSS_OFF, red[0]);
            __threadfence();
            const unsigned arr = __hip_atomic_fetch_add(&bar[2], 1u, __ATOMIC_ACQ_REL,
                                                        __HIP_MEMORY_SCOPE_AGENT);
            if (arr == GRID_B - 1) {
                // last block finalizes: all loss adds are ordered-before via bar[2]
                const float l = __hip_atomic_load(ws + LOSS_OFF, __ATOMIC_RELAXED,
                                                  __HIP_MEMORY_SCOPE_AGENT);
                out[0] = l * 0.25f;            // mean over 4 images
            }
        }
    }
}

extern "C" void kernel_launch(void* const* d_in, const int* in_sizes, int n_in,
                              void* d_out, int out_size, void* d_ws, size_t ws_size,
                              hipStream_t stream) {
    const float* emb = (const float*)d_in[0];
    const int* target = (const int*)d_in[1];
    float* out = (float*)d_out;
    float* ws = (float*)d_ws;

    hipMemsetAsync(d_ws, 0, WS_FLOATS * sizeof(float), stream);
    k_fused<<<dim3(GRID_B), 256, 0, stream>>>(emb, target, ws, out);
}

// Round 10
// 174.314 us; speedup vs baseline: 1.5728x; 1.5728x over previous
//
#include <hip/hip_runtime.h>

#define N_IMG 4
#define E_DIM 16
#define G_PIX 80000               // float4 groups per image-channel (320000/4)
#define C_CLS 20
#define CK 19                     // classes 1..19 (IGNORE = 0)
#define NREP 8                    // LDS replica count for atomic binning
#define EG 8                      // channels per k_sums block
#define NEG (E_DIM / EG)          // 2 channel groups
#define SL1 128                   // pixel slices per (image, egroup)
#define R1 (G_PIX / SL1)          // 625 groups per k_sums block (exact)
#define GRID1 (SL1 * NEG * N_IMG) // 1024 blocks = 4 per CU
#define SL2 256                   // k_var slices per image
#define R2 ((G_PIX + SL2 - 1) / SL2) // 313 (tail-checked)
#define GRID2 (SL2 * N_IMG)       // 1024 blocks
#define MSTRIDE 17                // lmean stride: 20 labels -> 20 distinct banks
#define LS_SLOT 9                 // u64 slots per (class, replica): 8 channels + pad
#define SCALE_F 16777216.0f       // 2^24 fixed-point scale
#define INV_SCALE (1.0f / 16777216.0f)

// ws float layout: sums[n][c][e], counts[n][c], loss, done-counter
#define SUMS_OFF 0
#define CNT_OFF (N_IMG * C_CLS * E_DIM)       // 1280
#define LOSS_OFF (CNT_OFF + N_IMG * C_CLS)    // 1360
#define DONE_OFF (LOSS_OFF + 1)               // 1361 (u32 done counter)
#define WS_FLOATS (DONE_OFF + 1)

static_assert(G_PIX % SL1 == 0, "k_sums slicing must be exact");

// ---------------- Kernel 1: per-class sums + counts via native integer LDS atomics ----------
// NOTE (measured r2): float LDS atomicAdd = CAS loop on gfx950 (310us vs 65us).
// Integer ds_add is native + fire-and-forget; values quantized at 2^24 fixed point.
// NOTE (measured r8): never cap MLP with unroll-1 batching — VGPR=28 run was latency-bound
// at 187us with VALUBusy 2.8%. Keep independent loads issued before use.
__global__ __launch_bounds__(256, 4) void k_sums(const float* __restrict__ emb,
                                                 const int* __restrict__ target,
                                                 float* __restrict__ ws) {
    __shared__ unsigned long long ls[C_CLS][NREP][LS_SLOT];   // 11520 B
    __shared__ unsigned int lc[C_CLS][NREP];                  // 640 B

    const int tid = threadIdx.x;
    const int b = blockIdx.x;
    const int n = b & 3;
    const int eg = (b >> 2) & (NEG - 1);
    const int slice = b >> 3;                  // 0..SL1-1
    const int e0 = eg * EG;

    unsigned long long* lsf = &ls[0][0][0];
    for (int i = tid; i < C_CLS * NREP * LS_SLOT; i += 256) lsf[i] = 0ull;
    for (int i = tid; i < C_CLS * NREP; i += 256) (&lc[0][0])[i] = 0u;
    __syncthreads();

    const float4* emb0 = (const float4*)emb + ((size_t)(n * E_DIM + e0)) * G_PIX;
    const int4* tgt4 = (const int4*)target + (size_t)n * G_PIX;
    const int r = tid & (NREP - 1);

#define QADD(p, idx, val) \
    atomicAdd((p) + (idx), (unsigned long long)(long long)__float2int_rn((val) * SCALE_F))

    const int g1 = (slice + 1) * R1;
    for (int g = slice * R1 + tid; g < g1; g += 256) {
        const int4 lb = tgt4[g];
        // all 9 loads independent -> issued before first use (MLP)
        float4 v[EG];
#pragma unroll
        for (int k = 0; k < EG; k++) v[k] = emb0[(size_t)k * G_PIX + g];

        unsigned long long* px = &ls[lb.x][r][0];
        unsigned long long* py = &ls[lb.y][r][0];
        unsigned long long* pz = &ls[lb.z][r][0];
        unsigned long long* pw = &ls[lb.w][r][0];
#pragma unroll
        for (int k = 0; k < EG; k++) {
            QADD(px, k, v[k].x);
            QADD(py, k, v[k].y);
            QADD(pz, k, v[k].z);
            QADD(pw, k, v[k].w);
        }
        if (eg == 0) {
            atomicAdd(&lc[lb.x][r], 1u); atomicAdd(&lc[lb.y][r], 1u);
            atomicAdd(&lc[lb.z][r], 1u); atomicAdd(&lc[lb.w][r], 1u);
        }
    }
#undef QADD
    __syncthreads();

    // flush: combine replicas, convert back to float, one global atomic per (c, e')
    for (int i = tid; i < C_CLS * EG; i += 256) {
        const int c = i >> 3, e1 = i & 7;
        long long q = 0;
#pragma unroll
        for (int rr = 0; rr < NREP; rr++) q += (long long)ls[c][rr][e1];
        atomicAdd(ws + SUMS_OFF + (n * C_CLS + c) * E_DIM + e0 + e1, (float)q * INV_SCALE);
    }
    if (eg == 0) {
        for (int c = tid; c < C_CLS; c += 256) {
            unsigned int s = 0;
#pragma unroll
            for (int rr = 0; rr < NREP; rr++) s += lc[c][rr];
            atomicAdd(ws + CNT_OFF + n * C_CLS + c, (float)s);
        }
    }
}

// -------- Kernel 2: means (per-block) + distance/reg terms (blocks 0..3) + variance term ----
// Last arriving block writes out[0] (no k_fin launch). Pattern verified absmax=0 in r8.
__global__ __launch_bounds__(256, 4) void k_var(const float* __restrict__ emb,
                                                const int* __restrict__ target,
                                                float* __restrict__ ws,
                                                float* __restrict__ out) {
    __shared__ float lmean[C_CLS * MSTRIDE];
    __shared__ float lw[C_CLS];
    __shared__ float red[256];

    const int tid = threadIdx.x;
    const int b = blockIdx.x;
    const int n = b & 3;
    const int s2 = b >> 2;                     // 0..SL2-1

    const float* gsum = ws + SUMS_OFF + n * C_CLS * E_DIM;
    const float* gcnt = ws + CNT_OFF + n * C_CLS;

    for (int i = tid; i < C_CLS * E_DIM; i += 256) {
        const int c = i >> 4, e = i & 15;
        const float cnt = gcnt[c];
        lmean[c * MSTRIDE + e] = (cnt > 0.f) ? gsum[i] / cnt : 0.f;
    }
    if (tid < C_CLS) {
        const float cnt = gcnt[tid];
        // lw[0] = 0 masks IGNORE pixels branchlessly
        lw[tid] = (tid != 0 && cnt > 0.f) ? 1.0f / (cnt * (float)CK) : 0.f;
    }
    __syncthreads();

    float acc = 0.f;
    if (b < N_IMG) {
        // one block per image computes push + regularizer terms
        for (int idx = tid; idx < CK * CK; idx += 256) {
            const int i = idx / CK + 1, j = idx % CK + 1;
            if (i != j) {
                float sq = 0.f;
#pragma unroll
                for (int e = 0; e < E_DIM; e++) {
                    const float d = lmean[i * MSTRIDE + e] - lmean[j * MSTRIDE + e];
                    sq += d * d;
                }
                const float dm = sqrtf(sq);
                const float h = fmaxf(3.0f - dm, 0.f);   // 2*DELTA_DIST = 3
                acc += h * h;
            }
        }
        acc *= 1.0f / (float)(CK * (CK - 1));            // BETA = 1
        float racc = 0.f;
        for (int c = tid + 1; c < C_CLS; c += 256) {
            float sq = 0.f;
#pragma unroll
            for (int e = 0; e < E_DIM; e++) {
                const float m = lmean[c * MSTRIDE + e];
                sq += m * m;
            }
            racc += sqrtf(sq);
        }
        acc += 0.001f * racc / (float)CK;                // GAMMA = 0.001
    }

    const float4* emb4 = (const float4*)emb + (size_t)n * E_DIM * G_PIX;
    const int4* tgt4 = (const int4*)target + (size_t)n * G_PIX;
    const int gend0 = (s2 + 1) * R2;
    const int gend = (gend0 < G_PIX) ? gend0 : G_PIX;
    for (int g = s2 * R2 + tid; g < gend; g += 256) {
        const int4 lb = tgt4[g];
        // all 16 channel loads issued before use (forced MLP — the r8 lesson)
        float4 v[E_DIM];
#pragma unroll
        for (int e = 0; e < E_DIM; e++) v[e] = emb4[(size_t)e * G_PIX + g];

        const int bx = lb.x * MSTRIDE, by = lb.y * MSTRIDE;
        const int bz = lb.z * MSTRIDE, bw = lb.w * MSTRIDE;
        float sx = 0.f, sy = 0.f, sz = 0.f, sw = 0.f;
#pragma unroll
        for (int e = 0; e < E_DIM; e++) {
            float d;
            d = v[e].x - lmean[bx + e]; sx += d * d;
            d = v[e].y - lmean[by + e]; sy += d * d;
            d = v[e].z - lmean[bz + e]; sz += d * d;
            d = v[e].w - lmean[bw + e]; sw += d * d;
        }
        float h;
        h = fmaxf(sqrtf(sx) - 0.5f, 0.f); acc += h * h * lw[lb.x];
        h = fmaxf(sqrtf(sy) - 0.5f, 0.f); acc += h * h * lw[lb.y];
        h = fmaxf(sqrtf(sz) - 0.5f, 0.f); acc += h * h * lw[lb.z];
        h = fmaxf(sqrtf(sw) - 0.5f, 0.f); acc += h * h * lw[lb.w];
    }

    red[tid] = acc;
    __syncthreads();
    for (int s = 128; s > 0; s >>= 1) {
        if (tid < s) red[tid] += red[tid + s];
        __syncthreads();
    }
    if (tid == 0) {
        atomicAdd(ws + LOSS_OFF, red[0]);
        __threadfence();
        unsigned* done = (unsigned*)(ws + DONE_OFF);
        const unsigned arr = __hip_atomic_fetch_add(done, 1u, __ATOMIC_ACQ_REL,
                                                    __HIP_MEMORY_SCOPE_AGENT);
        if (arr == GRID2 - 1) {
            // last block: all loss adds ordered-before via the done counter
            const float l = __hip_atomic_load(ws + LOSS_OFF, __ATOMIC_RELAXED,
                                              __HIP_MEMORY_SCOPE_AGENT);
            out[0] = l * 0.25f;                // mean over 4 images
        }
    }
}

extern "C" void kernel_launch(void* const* d_in, const int* in_sizes, int n_in,
                              void* d_out, int out_size, void* d_ws, size_t ws_size,
                              hipStream_t stream) {
    const float* emb = (const float*)d_in[0];
    const int* target = (const int*)d_in[1];
    float* out = (float*)d_out;
    float* ws = (float*)d_ws;

    hipMemsetAsync(d_ws, 0, WS_FLOATS * sizeof(float), stream);
    k_sums<<<dim3(GRID1), 256, 0, stream>>>(emb, target, ws);
    k_var<<<dim3(GRID2), 256, 0, stream>>>(emb, target, ws, out);
}

// Round 19
// 137.903 us; speedup vs baseline: 1.9881x; 1.2640x over previous
//
#include <hip/hip_runtime.h>

#define N_IMG 4
#define E_DIM 16
#define G_PIX 80000               // float4 groups per image-channel (320000/4)
#define C_CLS 20
#define CK 19                     // classes 1..19 (IGNORE = 0)
#define NREP 8                    // LDS replica count for atomic binning
#define EG 8                      // channels per k_sums block
#define NEG (E_DIM / EG)          // 2 channel groups
#define SL1 128                   // pixel slices per (image, egroup)
#define R1 (G_PIX / SL1)          // 625 groups per k_sums block (exact)
#define GRID1 (SL1 * NEG * N_IMG) // 1024 blocks = 4 per CU
#define SL2 256                   // k_var slices per image
#define R2 ((G_PIX + SL2 - 1) / SL2) // 313 (tail-checked)
#define GRID2 (SL2 * N_IMG)       // 1024 blocks
#define MSTRIDE 17                // lmean stride: 20 labels -> 20 distinct banks
#define LS_SLOT 9                 // u64 slots per (class, replica): 8 channels + pad
#define SCALE_F 16777216.0f       // 2^24 fixed-point scale
#define INV_SCALE (1.0f / 16777216.0f)

// ws layout (BYTES). All-integer accumulators: global FLOAT atomicAdd compiles to a
// CAS retry loop without -munsafe-fp-atomics (measured r10: k_var flat 55us whether
// FETCH=44MB or 65KB, occupancy 17.6% -> serialized epilogue). Integer atomics are native.
#define SUMS_OFF 0                                  // i64[4][20][16]   10240 B
#define CNT_OFF  (N_IMG * C_CLS * E_DIM * 8)        // u32[4][20]       320 B
#define PART_OFF (CNT_OFF + N_IMG * C_CLS * 4)      // float[1024]      4096 B
#define WS_BYTES (PART_OFF + GRID2 * 4)

static_assert(G_PIX % SL1 == 0, "k_sums slicing must be exact");

// ---------------- Kernel 1: per-class sums + counts via native integer atomics ----------
// NOTE (measured r2): float LDS atomicAdd = CAS loop on gfx950 (310us vs 65us).
// NOTE (measured r8): never cap MLP — keep independent loads issued before use.
// NOTE (measured r10): float GLOBAL atomicAdd is also a CAS loop -> flush as u64/u32.
__global__ __launch_bounds__(256, 4) void k_sums(const float* __restrict__ emb,
                                                 const int* __restrict__ target,
                                                 char* __restrict__ wsb) {
    __shared__ unsigned long long ls[C_CLS][NREP][LS_SLOT];   // 11520 B
    __shared__ unsigned int lc[C_CLS][NREP];                  // 640 B

    const int tid = threadIdx.x;
    const int b = blockIdx.x;
    const int n = b & 3;
    const int eg = (b >> 2) & (NEG - 1);
    const int slice = b >> 3;                  // 0..SL1-1
    const int e0 = eg * EG;

    unsigned long long* lsf = &ls[0][0][0];
    for (int i = tid; i < C_CLS * NREP * LS_SLOT; i += 256) lsf[i] = 0ull;
    for (int i = tid; i < C_CLS * NREP; i += 256) (&lc[0][0])[i] = 0u;
    __syncthreads();

    const float4* emb0 = (const float4*)emb + ((size_t)(n * E_DIM + e0)) * G_PIX;
    const int4* tgt4 = (const int4*)target + (size_t)n * G_PIX;
    const int r = tid & (NREP - 1);

#define QADD(p, idx, val) \
    atomicAdd((p) + (idx), (unsigned long long)(long long)__float2int_rn((val) * SCALE_F))

    const int g1 = (slice + 1) * R1;
    for (int g = slice * R1 + tid; g < g1; g += 256) {
        const int4 lb = tgt4[g];
        // all 9 loads independent -> issued before first use (MLP)
        float4 v[EG];
#pragma unroll
        for (int k = 0; k < EG; k++) v[k] = emb0[(size_t)k * G_PIX + g];

        unsigned long long* px = &ls[lb.x][r][0];
        unsigned long long* py = &ls[lb.y][r][0];
        unsigned long long* pz = &ls[lb.z][r][0];
        unsigned long long* pw = &ls[lb.w][r][0];
#pragma unroll
        for (int k = 0; k < EG; k++) {
            QADD(px, k, v[k].x);
            QADD(py, k, v[k].y);
            QADD(pz, k, v[k].z);
            QADD(pw, k, v[k].w);
        }
        if (eg == 0) {
            atomicAdd(&lc[lb.x][r], 1u); atomicAdd(&lc[lb.y][r], 1u);
            atomicAdd(&lc[lb.z][r], 1u); atomicAdd(&lc[lb.w][r], 1u);
        }
    }
#undef QADD
    __syncthreads();

    // flush: combine replicas, native u64 atomic to global (fire-and-forget, no CAS)
    unsigned long long* gsum = (unsigned long long*)(wsb + SUMS_OFF);
    unsigned int* gcnt = (unsigned int*)(wsb + CNT_OFF);
    for (int i = tid; i < C_CLS * EG; i += 256) {
        const int c = i >> 3, e1 = i & 7;
        unsigned long long q = 0ull;
#pragma unroll
        for (int rr = 0; rr < NREP; rr++) q += ls[c][rr][e1];
        atomicAdd(&gsum[(n * C_CLS + c) * E_DIM + e0 + e1], q);
    }
    if (eg == 0) {
        for (int c = tid; c < C_CLS; c += 256) {
            unsigned int s = 0;
#pragma unroll
            for (int rr = 0; rr < NREP; rr++) s += lc[c][rr];
            atomicAdd(&gcnt[n * C_CLS + c], s);
        }
    }
}

// -------- Kernel 2: means (per-block) + distance/reg terms (blocks 0..3) + variance term ----
// Epilogue: plain store of the block partial to its own slot. ZERO atomics, no fence.
__global__ __launch_bounds__(256, 4) void k_var(const float* __restrict__ emb,
                                                const int* __restrict__ target,
                                                char* __restrict__ wsb) {
    __shared__ float lmean[C_CLS * MSTRIDE];
    __shared__ float lw[C_CLS];
    __shared__ float red[256];

    const int tid = threadIdx.x;
    const int b = blockIdx.x;
    const int n = b & 3;
    const int s2 = b >> 2;                     // 0..SL2-1

    const long long* gsum = (const long long*)(wsb + SUMS_OFF);
    const unsigned int* gcnt = (const unsigned int*)(wsb + CNT_OFF);

    for (int i = tid; i < C_CLS * E_DIM; i += 256) {
        const int c = i >> 4, e = i & 15;
        const float cnt = (float)gcnt[n * C_CLS + c];
        const float s = (float)gsum[n * C_CLS * E_DIM + i] * INV_SCALE;
        lmean[c * MSTRIDE + e] = (cnt > 0.f) ? s / cnt : 0.f;
    }
    if (tid < C_CLS) {
        const float cnt = (float)gcnt[n * C_CLS + tid];
        // lw[0] = 0 masks IGNORE pixels branchlessly
        lw[tid] = (tid != 0 && cnt > 0.f) ? 1.0f / (cnt * (float)CK) : 0.f;
    }
    __syncthreads();

    float acc = 0.f;
    if (b < N_IMG) {
        // one block per image computes push + regularizer terms
        for (int idx = tid; idx < CK * CK; idx += 256) {
            const int i = idx / CK + 1, j = idx % CK + 1;
            if (i != j) {
                float sq = 0.f;
#pragma unroll
                for (int e = 0; e < E_DIM; e++) {
                    const float d = lmean[i * MSTRIDE + e] - lmean[j * MSTRIDE + e];
                    sq += d * d;
                }
                const float dm = sqrtf(sq);
                const float h = fmaxf(3.0f - dm, 0.f);   // 2*DELTA_DIST = 3
                acc += h * h;
            }
        }
        acc *= 1.0f / (float)(CK * (CK - 1));            // BETA = 1
        float racc = 0.f;
        for (int c = tid + 1; c < C_CLS; c += 256) {
            float sq = 0.f;
#pragma unroll
            for (int e = 0; e < E_DIM; e++) {
                const float m = lmean[c * MSTRIDE + e];
                sq += m * m;
            }
            racc += sqrtf(sq);
        }
        acc += 0.001f * racc / (float)CK;                // GAMMA = 0.001
    }

    const float4* emb4 = (const float4*)emb + (size_t)n * E_DIM * G_PIX;
    const int4* tgt4 = (const int4*)target + (size_t)n * G_PIX;
    const int gend0 = (s2 + 1) * R2;
    const int gend = (gend0 < G_PIX) ? gend0 : G_PIX;
    for (int g = s2 * R2 + tid; g < gend; g += 256) {
        const int4 lb = tgt4[g];
        // all 16 channel loads issued before use (forced MLP — the r8 lesson)
        float4 v[E_DIM];
#pragma unroll
        for (int e = 0; e < E_DIM; e++) v[e] = emb4[(size_t)e * G_PIX + g];

        const int bx = lb.x * MSTRIDE, by = lb.y * MSTRIDE;
        const int bz = lb.z * MSTRIDE, bw = lb.w * MSTRIDE;
        float sx = 0.f, sy = 0.f, sz = 0.f, sw = 0.f;
#pragma unroll
        for (int e = 0; e < E_DIM; e++) {
            float d;
            d = v[e].x - lmean[bx + e]; sx += d * d;
            d = v[e].y - lmean[by + e]; sy += d * d;
            d = v[e].z - lmean[bz + e]; sz += d * d;
            d = v[e].w - lmean[bw + e]; sw += d * d;
        }
        float h;
        h = fmaxf(sqrtf(sx) - 0.5f, 0.f); acc += h * h * lw[lb.x];
        h = fmaxf(sqrtf(sy) - 0.5f, 0.f); acc += h * h * lw[lb.y];
        h = fmaxf(sqrtf(sz) - 0.5f, 0.f); acc += h * h * lw[lb.z];
        h = fmaxf(sqrtf(sw) - 0.5f, 0.f); acc += h * h * lw[lb.w];
    }

    red[tid] = acc;
    __syncthreads();
    for (int s = 128; s > 0; s >>= 1) {
        if (tid < s) red[tid] += red[tid + s];
        __syncthreads();
    }
    if (tid == 0) ((float*)(wsb + PART_OFF))[b] = red[0];   // plain store, own slot
}

// ---------------- Kernel 3: finalize (sum 1024 partials) ----------------
__global__ void k_fin(const char* __restrict__ wsb, float* __restrict__ out) {
    __shared__ float red[256];
    const int tid = threadIdx.x;
    const float* part = (const float*)(wsb + PART_OFF);
    float a = 0.f;
#pragma unroll
    for (int i = 0; i < GRID2 / 256; i++) a += part[i * 256 + tid];
    red[tid] = a;
    __syncthreads();
    for (int s = 128; s > 0; s >>= 1) {
        if (tid < s) red[tid] += red[tid + s];
        __syncthreads();
    }
    if (tid == 0) out[0] = red[0] * 0.25f;     // mean over 4 images
}

extern "C" void kernel_launch(void* const* d_in, const int* in_sizes, int n_in,
                              void* d_out, int out_size, void* d_ws, size_t ws_size,
                              hipStream_t stream) {
    const float* emb = (const float*)d_in[0];
    const int* target = (const int*)d_in[1];
    float* out = (float*)d_out;
    char* wsb = (char*)d_ws;

    hipMemsetAsync(d_ws, 0, WS_BYTES, stream);
    k_sums<<<dim3(GRID1), 256, 0, stream>>>(emb, target, wsb);
    k_var<<<dim3(GRID2), 256, 0, stream>>>(emb, target, wsb);
    k_fin<<<1, 256, 0, stream>>>(wsb, out);
}